// Round 2
// baseline (673.466 us; speedup 1.0000x reference)
//
#include <hip/hip_runtime.h>

#define FMAX 1024
#define NC 16       // channels
#define NB 16       // batch
#define HW (512 * 512)

constexpr int CHUNKS = 16;                      // pixel chunks per image
constexpr int PIX_PER_CHUNK = HW / CHUNKS;      // 16384
constexpr int ATHREADS = 512;

// ---------------------------------------------------------------------------
// Kernel 1: accumulate per-field logits sums (LDS-staged) + label histogram
// ---------------------------------------------------------------------------
__global__ __launch_bounds__(ATHREADS) void accum_kernel(
    const float* __restrict__ logits,   // (B, C, HW)
    const int* __restrict__ masks,      // (B, HW)
    const int* __restrict__ fids,       // (B, HW)
    float* __restrict__ sums,           // (B, FMAX, C)
    int* __restrict__ hist)             // (B, FMAX, C)
{
    __shared__ float lsum[FMAX * NC];   // 64 KB

    const int b = blockIdx.x / CHUNKS;
    const int chunk = blockIdx.x % CHUNKS;
    const int p0 = chunk * PIX_PER_CHUNK;

    for (int i = threadIdx.x; i < FMAX * NC; i += ATHREADS) lsum[i] = 0.0f;
    __syncthreads();

    const float* lg    = logits + (size_t)b * NC * HW;
    const int*   fid_b = fids  + (size_t)b * HW;
    const int*   lab_b = masks + (size_t)b * HW;
    int*         hst_b = hist  + (size_t)b * FMAX * NC;

    for (int i = threadIdx.x; i < PIX_PER_CHUNK; i += ATHREADS) {
        const int p   = p0 + i;
        const int f   = fid_b[p];
        const int lab = lab_b[p];
        atomicAdd(&hst_b[f * NC + lab], 1);
        const int base = f * NC;
        #pragma unroll
        for (int c = 0; c < NC; ++c) {
            atomicAdd(&lsum[base + c], lg[(size_t)c * HW + p]);
        }
    }
    __syncthreads();

    float* sums_b = sums + (size_t)b * FMAX * NC;
    for (int i = threadIdx.x; i < FMAX * NC; i += ATHREADS) {
        const float v = lsum[i];
        if (v != 0.0f) atomicAdd(&sums_b[i], v);
    }
}

// ---------------------------------------------------------------------------
// Kernel 2: per-(b,field) CE against histogram-mode label
// ---------------------------------------------------------------------------
__global__ __launch_bounds__(256) void finalize_kernel(
    const float* __restrict__ sums,
    const int* __restrict__ hist,
    float* __restrict__ tot_n)          // [0]=total ce, [1]=count
{
    const int idx = blockIdx.x * blockDim.x + threadIdx.x;
    if (idx >= NB * FMAX) return;
    const int f = idx & (FMAX - 1);

    const float* s = sums + (size_t)idx * NC;
    const int*   h = hist + (size_t)idx * NC;

    int   hv[NC];
    float sv[NC];
    int cnt = 0;
    #pragma unroll
    for (int c = 0; c < NC; ++c) {
        hv[c] = h[c];
        sv[c] = s[c];
        cnt += hv[c];
    }
    if (f == 0 || cnt == 0) return;     // fid 0 = "no field", excluded

    // first-occurrence argmax (matches jnp.argmax tie-break)
    int ma = 0;
    #pragma unroll
    for (int c = 1; c < NC; ++c) if (hv[c] > hv[ma]) ma = c;
    int mv = 1;
    #pragma unroll
    for (int c = 2; c < NC; ++c) if (hv[c] > hv[mv]) mv = c;
    int vcnt = 0;
    #pragma unroll
    for (int c = 1; c < NC; ++c) vcnt += hv[c];
    const int label = (vcnt > 0) ? mv : ma;

    const float inv = 1.0f / (float)cnt;
    float mean[NC];
    float m = -1e30f;
    #pragma unroll
    for (int c = 0; c < NC; ++c) {
        mean[c] = sv[c] * inv;
        m = fmaxf(m, mean[c]);
    }
    float se = 0.0f;
    #pragma unroll
    for (int c = 0; c < NC; ++c) se += expf(mean[c] - m);
    const float logz = m + logf(se);

    float picked = 0.0f;
    #pragma unroll
    for (int c = 0; c < NC; ++c) picked = (c == label) ? mean[c] : picked;

    const float ce = logz - picked;
    atomicAdd(&tot_n[0], ce);
    atomicAdd(&tot_n[1], 1.0f);
}

// ---------------------------------------------------------------------------
// Kernel 3: final scalar
// ---------------------------------------------------------------------------
__global__ void out_kernel(const float* __restrict__ tot_n, float* __restrict__ out)
{
    const float n = tot_n[1];
    out[0] = (n > 0.0f) ? (tot_n[0] / n) : 0.0f;
}

// ---------------------------------------------------------------------------
extern "C" void kernel_launch(void* const* d_in, const int* in_sizes, int n_in,
                              void* d_out, int out_size, void* d_ws, size_t ws_size,
                              hipStream_t stream)
{
    const float* logits = (const float*)d_in[0];
    const int*   masks  = (const int*)d_in[1];
    const int*   fids   = (const int*)d_in[2];

    const size_t sums_bytes = (size_t)NB * FMAX * NC * sizeof(float);   // 1 MiB
    float* sums  = (float*)d_ws;
    int*   hist  = (int*)((char*)d_ws + sums_bytes);
    float* tot_n = (float*)((char*)d_ws + 2 * sums_bytes);

    hipMemsetAsync(d_ws, 0, 2 * sums_bytes + 2 * sizeof(float), stream);

    accum_kernel<<<NB * CHUNKS, ATHREADS, 0, stream>>>(logits, masks, fids, sums, hist);
    finalize_kernel<<<(NB * FMAX + 255) / 256, 256, 0, stream>>>(sums, hist, tot_n);
    out_kernel<<<1, 1, 0, stream>>>(tot_n, (float*)d_out);
}

// Round 4
// 648.230 us; speedup vs baseline: 1.0389x; 1.0389x over previous
//
#include <hip/hip_runtime.h>

#define FMAX 1024
#define NC 16       // channels
#define NB 16       // batch
#define HW (512 * 512)

constexpr int CHS = 32;              // pixel chunks per image, sums kernel
constexpr int CHH = 16;              // pixel chunks per image, hist kernel
constexpr int T   = 512;             // threads per block (accum kernels)

// workspace layout:
//   psums : NB*CHS * NC*FMAX floats = 32 MiB
//   phist : NB*CHH * NC*FMAX ints   = 16 MiB
//   tot_n : 2 floats

// ---------------------------------------------------------------------------
// Kernel 1: per-(image,chunk) field sums of logits, LDS-staged, plain dump
// ---------------------------------------------------------------------------
__global__ __launch_bounds__(T) void sums_kernel(
    const float* __restrict__ logits,   // (B, C, HW)
    const int* __restrict__ fids,       // (B, HW)
    float* __restrict__ psums)          // (B*CHS, NC, FMAX)
{
    __shared__ float lsum[NC * FMAX];   // 64 KB, layout [c][f] -> bank = f%32

    const int b  = blockIdx.x / CHS;
    const int ch = blockIdx.x % CHS;
    constexpr int PPB = HW / CHS;       // 8192 pixels per block
    const int p0 = ch * PPB;

    for (int i = threadIdx.x; i < NC * FMAX; i += T) lsum[i] = 0.0f;
    __syncthreads();

    const float* lg = logits + (size_t)b * NC * HW + p0;
    const int*   fb = fids   + (size_t)b * HW + p0;

    constexpr int PASSES = PPB / (T * 4);   // 4
    #pragma unroll
    for (int pass = 0; pass < PASSES; ++pass) {
        const int i4 = (pass * T + threadIdx.x) * 4;
        const int4 f4 = *reinterpret_cast<const int4*>(fb + i4);
        #pragma unroll
        for (int c = 0; c < NC; ++c) {
            const float4 v = *reinterpret_cast<const float4*>(lg + (size_t)c * HW + i4);
            atomicAdd(&lsum[c * FMAX + f4.x], v.x);
            atomicAdd(&lsum[c * FMAX + f4.y], v.y);
            atomicAdd(&lsum[c * FMAX + f4.z], v.z);
            atomicAdd(&lsum[c * FMAX + f4.w], v.w);
        }
    }
    __syncthreads();

    float* out = psums + (size_t)blockIdx.x * NC * FMAX;
    for (int i = threadIdx.x; i < NC * FMAX / 4; i += T)
        reinterpret_cast<float4*>(out)[i] = reinterpret_cast<const float4*>(lsum)[i];
}

// ---------------------------------------------------------------------------
// Kernel 2: per-(image,chunk) (field,label) histogram, LDS-staged, plain dump
// ---------------------------------------------------------------------------
__global__ __launch_bounds__(T) void hist_kernel(
    const int* __restrict__ masks,      // (B, HW)
    const int* __restrict__ fids,       // (B, HW)
    int* __restrict__ phist)            // (B*CHH, NC, FMAX)
{
    __shared__ int lh[NC * FMAX];       // 64 KB, layout [lab][f]

    const int b  = blockIdx.x / CHH;
    const int ch = blockIdx.x % CHH;
    constexpr int PPB = HW / CHH;       // 16384
    const int p0 = ch * PPB;

    for (int i = threadIdx.x; i < NC * FMAX; i += T) lh[i] = 0;
    __syncthreads();

    const int* fb = fids  + (size_t)b * HW + p0;
    const int* lb = masks + (size_t)b * HW + p0;

    constexpr int PASSES = PPB / (T * 4);   // 8
    #pragma unroll
    for (int pass = 0; pass < PASSES; ++pass) {
        const int i4 = (pass * T + threadIdx.x) * 4;
        const int4 f4 = *reinterpret_cast<const int4*>(fb + i4);
        const int4 l4 = *reinterpret_cast<const int4*>(lb + i4);
        atomicAdd(&lh[l4.x * FMAX + f4.x], 1);
        atomicAdd(&lh[l4.y * FMAX + f4.y], 1);
        atomicAdd(&lh[l4.z * FMAX + f4.z], 1);
        atomicAdd(&lh[l4.w * FMAX + f4.w], 1);
    }
    __syncthreads();

    int* out = phist + (size_t)blockIdx.x * NC * FMAX;
    for (int i = threadIdx.x; i < NC * FMAX / 4; i += T)
        reinterpret_cast<int4*>(out)[i] = reinterpret_cast<const int4*>(lh)[i];
}

// ---------------------------------------------------------------------------
// Kernel 3: reduce partials, per-(b,field) CE vs mode label, block-reduced
// ---------------------------------------------------------------------------
__global__ __launch_bounds__(256) void finalize_kernel(
    const float* __restrict__ psums,
    const int* __restrict__ phist,
    float* __restrict__ tot_n)          // [0]=total ce, [1]=count
{
    const int idx = blockIdx.x * 256 + threadIdx.x;   // b*FMAX + f
    const int b = idx >> 10;
    const int f = idx & (FMAX - 1);

    float sv[NC];
    int   hv[NC];
    #pragma unroll
    for (int c = 0; c < NC; ++c) { sv[c] = 0.0f; hv[c] = 0; }

    for (int ch = 0; ch < CHS; ++ch) {
        const float* p = psums + (size_t)(b * CHS + ch) * NC * FMAX + f;
        #pragma unroll
        for (int c = 0; c < NC; ++c) sv[c] += p[(size_t)c * FMAX];
    }
    for (int ch = 0; ch < CHH; ++ch) {
        const int* p = phist + (size_t)(b * CHH + ch) * NC * FMAX + f;
        #pragma unroll
        for (int c = 0; c < NC; ++c) hv[c] += p[(size_t)c * FMAX];
    }

    int cnt = 0;
    #pragma unroll
    for (int c = 0; c < NC; ++c) cnt += hv[c];

    float ce = 0.0f;
    float w  = 0.0f;
    if (f != 0 && cnt > 0) {
        // first-occurrence argmax (matches jnp.argmax tie-break)
        int ma = 0;
        #pragma unroll
        for (int c = 1; c < NC; ++c) if (hv[c] > hv[ma]) ma = c;
        int mv = 1;
        #pragma unroll
        for (int c = 2; c < NC; ++c) if (hv[c] > hv[mv]) mv = c;
        int vcnt = 0;
        #pragma unroll
        for (int c = 1; c < NC; ++c) vcnt += hv[c];
        const int label = (vcnt > 0) ? mv : ma;

        const float inv = 1.0f / (float)cnt;
        float mean[NC];
        float m = -1e30f;
        #pragma unroll
        for (int c = 0; c < NC; ++c) {
            mean[c] = sv[c] * inv;
            m = fmaxf(m, mean[c]);
        }
        float se = 0.0f;
        #pragma unroll
        for (int c = 0; c < NC; ++c) se += expf(mean[c] - m);
        const float logz = m + logf(se);

        float picked = 0.0f;
        #pragma unroll
        for (int c = 0; c < NC; ++c) picked = (c == label) ? mean[c] : picked;

        ce = logz - picked;
        w  = 1.0f;
    }

    // block reduction: wave shuffle then LDS, 2 atomics per block
    #pragma unroll
    for (int off = 32; off > 0; off >>= 1) {
        ce += __shfl_down(ce, off, 64);
        w  += __shfl_down(w,  off, 64);
    }
    __shared__ float rce[4], rw[4];
    const int wid  = threadIdx.x >> 6;
    const int lane = threadIdx.x & 63;
    if (lane == 0) { rce[wid] = ce; rw[wid] = w; }
    __syncthreads();
    if (threadIdx.x == 0) {
        float tce = rce[0] + rce[1] + rce[2] + rce[3];
        float tw  = rw[0]  + rw[1]  + rw[2]  + rw[3];
        atomicAdd(&tot_n[0], tce);
        atomicAdd(&tot_n[1], tw);
    }
}

// ---------------------------------------------------------------------------
// Kernel 4: final scalar
// ---------------------------------------------------------------------------
__global__ void out_kernel(const float* __restrict__ tot_n, float* __restrict__ out)
{
    const float n = tot_n[1];
    out[0] = (n > 0.0f) ? (tot_n[0] / n) : 0.0f;
}

// ---------------------------------------------------------------------------
extern "C" void kernel_launch(void* const* d_in, const int* in_sizes, int n_in,
                              void* d_out, int out_size, void* d_ws, size_t ws_size,
                              hipStream_t stream)
{
    const float* logits = (const float*)d_in[0];
    const int*   masks  = (const int*)d_in[1];
    const int*   fids   = (const int*)d_in[2];

    const size_t psums_bytes = (size_t)NB * CHS * NC * FMAX * sizeof(float);  // 32 MiB
    const size_t phist_bytes = (size_t)NB * CHH * NC * FMAX * sizeof(int);    // 16 MiB
    float* psums = (float*)d_ws;
    int*   phist = (int*)((char*)d_ws + psums_bytes);
    float* tot_n = (float*)((char*)d_ws + psums_bytes + phist_bytes);

    hipMemsetAsync(tot_n, 0, 2 * sizeof(float), stream);

    sums_kernel<<<NB * CHS, T, 0, stream>>>(logits, fids, psums);
    hist_kernel<<<NB * CHH, T, 0, stream>>>(masks, fids, phist);
    finalize_kernel<<<NB * FMAX / 256, 256, 0, stream>>>(psums, phist, tot_n);
    out_kernel<<<1, 1, 0, stream>>>(tot_n, (float*)d_out);
}

// Round 11
// 437.912 us; speedup vs baseline: 1.5379x; 1.4803x over previous
//
#include <hip/hip_runtime.h>

#define FMAX 1024
#define NC 16       // channels
#define NB 16       // batch
#define HW (512 * 512)

constexpr int CHS = 32;              // pixel chunks per image, sums kernel
constexpr int CHH = 16;              // pixel chunks per image, hist kernel
constexpr int T   = 512;             // threads per block (accum kernels)
constexpr int CGRP = 8;              // channels per sums block (c-split)

// Fixed-point scale for logit accumulation: int32 native LDS atomics
// (atomicAdd(float*) on LDS compiles to a CAS loop; int is ds_add_u32).
// |cell sum| < ~40px * 5.7 * 2^18 = 6e7 per chunk, < 6e8 per image: safe.
constexpr float FSCALE     = 262144.0f;          // 2^18
constexpr float FSCALE_INV = 1.0f / FSCALE;

// workspace layout:
//   psums : (NB*CHS*2) slabs of [FMAX][8] int32 = 32 MiB
//   phist : (NB*CHH) slabs of [FMAX][16] int32  = 16 MiB
//   tot_n : 2 floats

// ---------------------------------------------------------------------------
// Kernel 1: per-(image,chunk,chalf) field sums of 8 channels, LDS-staged,
// fixed-point int32 accumulation (native ds_add), 32 KB LDS -> 4 blocks/CU.
// ---------------------------------------------------------------------------
__global__ __launch_bounds__(T, 8) void sums_kernel(
    const float* __restrict__ logits,   // (B, C, HW)
    const int* __restrict__ fids,       // (B, HW)
    int* __restrict__ psums)            // (B*CHS*2) x [FMAX][CGRP]
{
    __shared__ int lsum[CGRP * FMAX];   // 32 KB, [c_local][f] -> bank = f%32

    const int cs = blockIdx.x & 1;              // channel half
    const int bc = blockIdx.x >> 1;             // b*CHS + ch
    const int b  = bc / CHS;
    const int ch = bc % CHS;
    constexpr int PPB = HW / CHS;               // 8192 pixels per block
    const int p0 = ch * PPB;

    for (int i = threadIdx.x; i < CGRP * FMAX; i += T) lsum[i] = 0;
    __syncthreads();

    const float* lg = logits + (size_t)b * NC * HW + (size_t)(cs * CGRP) * HW + p0;
    const int*   fb = fids   + (size_t)b * HW + p0;

    constexpr int PASSES = PPB / (T * 4);       // 4
    #pragma unroll
    for (int pass = 0; pass < PASSES; ++pass) {
        const int i4 = (pass * T + threadIdx.x) * 4;
        const int4 f4 = *reinterpret_cast<const int4*>(fb + i4);
        #pragma unroll
        for (int c = 0; c < CGRP; ++c) {
            const float4 v = *reinterpret_cast<const float4*>(lg + (size_t)c * HW + i4);
            atomicAdd(&lsum[c * FMAX + f4.x], __float2int_rn(v.x * FSCALE));
            atomicAdd(&lsum[c * FMAX + f4.y], __float2int_rn(v.y * FSCALE));
            atomicAdd(&lsum[c * FMAX + f4.z], __float2int_rn(v.z * FSCALE));
            atomicAdd(&lsum[c * FMAX + f4.w], __float2int_rn(v.w * FSCALE));
        }
    }
    __syncthreads();

    // dump transposed: slab row f holds 8 consecutive channel sums (32B)
    int* out = psums + (size_t)blockIdx.x * (FMAX * CGRP);
    for (int j = threadIdx.x; j < FMAX * CGRP / 4; j += T) {
        const int f  = j >> 1;              // 2 int4 per row
        const int c0 = (j & 1) * 4;
        int4 v;
        v.x = lsum[(c0 + 0) * FMAX + f];
        v.y = lsum[(c0 + 1) * FMAX + f];
        v.z = lsum[(c0 + 2) * FMAX + f];
        v.w = lsum[(c0 + 3) * FMAX + f];
        reinterpret_cast<int4*>(out)[j] = v;
    }
}

// ---------------------------------------------------------------------------
// Kernel 2: per-(image,chunk) (field,label) histogram, LDS-staged
// ---------------------------------------------------------------------------
__global__ __launch_bounds__(T) void hist_kernel(
    const int* __restrict__ masks,      // (B, HW)
    const int* __restrict__ fids,       // (B, HW)
    int* __restrict__ phist)            // (B*CHH) x [FMAX][NC]
{
    __shared__ int lh[NC * FMAX];       // 64 KB, [lab][f]

    const int b  = blockIdx.x / CHH;
    const int ch = blockIdx.x % CHH;
    constexpr int PPB = HW / CHH;       // 16384
    const int p0 = ch * PPB;

    for (int i = threadIdx.x; i < NC * FMAX; i += T) lh[i] = 0;
    __syncthreads();

    const int* fb = fids  + (size_t)b * HW + p0;
    const int* lb = masks + (size_t)b * HW + p0;

    constexpr int PASSES = PPB / (T * 4);   // 8
    #pragma unroll
    for (int pass = 0; pass < PASSES; ++pass) {
        const int i4 = (pass * T + threadIdx.x) * 4;
        const int4 f4 = *reinterpret_cast<const int4*>(fb + i4);
        const int4 l4 = *reinterpret_cast<const int4*>(lb + i4);
        atomicAdd(&lh[l4.x * FMAX + f4.x], 1);
        atomicAdd(&lh[l4.y * FMAX + f4.y], 1);
        atomicAdd(&lh[l4.z * FMAX + f4.z], 1);
        atomicAdd(&lh[l4.w * FMAX + f4.w], 1);
    }
    __syncthreads();

    // dump transposed: slab row f holds 16 consecutive label counts (64B)
    int* out = phist + (size_t)blockIdx.x * (FMAX * NC);
    for (int j = threadIdx.x; j < FMAX * NC / 4; j += T) {
        const int f  = j >> 2;
        const int c0 = (j & 3) * 4;
        int4 v;
        v.x = lh[(c0 + 0) * FMAX + f];
        v.y = lh[(c0 + 1) * FMAX + f];
        v.z = lh[(c0 + 2) * FMAX + f];
        v.w = lh[(c0 + 3) * FMAX + f];
        reinterpret_cast<int4*>(out)[j] = v;
    }
}

// ---------------------------------------------------------------------------
// Kernel 3: reduce partials (coalesced), per-(b,field) CE vs mode label
// ---------------------------------------------------------------------------
__global__ __launch_bounds__(256) void finalize_kernel(
    const int* __restrict__ psums,
    const int* __restrict__ phist,
    float* __restrict__ tot_n)          // [0]=total ce, [1]=count
{
    const int idx = blockIdx.x * 256 + threadIdx.x;   // b*FMAX + f
    const int b = idx >> 10;
    const int f = idx & (FMAX - 1);

    int si[NC];
    int hv[NC];
    #pragma unroll
    for (int c = 0; c < NC; ++c) { si[c] = 0; hv[c] = 0; }

    // psums: slab (b*CHS+ch)*2+cs, row f = 8 contiguous ints (2 x int4)
    for (int ch = 0; ch < CHS; ++ch) {
        #pragma unroll
        for (int cs = 0; cs < 2; ++cs) {
            const int* p = psums + ((size_t)((b * CHS + ch) * 2 + cs)) * (FMAX * CGRP)
                         + (size_t)f * CGRP;
            const int4 a = reinterpret_cast<const int4*>(p)[0];
            const int4 d = reinterpret_cast<const int4*>(p)[1];
            si[cs * 8 + 0] += a.x; si[cs * 8 + 1] += a.y;
            si[cs * 8 + 2] += a.z; si[cs * 8 + 3] += a.w;
            si[cs * 8 + 4] += d.x; si[cs * 8 + 5] += d.y;
            si[cs * 8 + 6] += d.z; si[cs * 8 + 7] += d.w;
        }
    }
    // phist: slab (b*CHH+ch), row f = 16 contiguous ints (4 x int4)
    for (int ch = 0; ch < CHH; ++ch) {
        const int* p = phist + ((size_t)(b * CHH + ch)) * (FMAX * NC) + (size_t)f * NC;
        #pragma unroll
        for (int k = 0; k < 4; ++k) {
            const int4 v = reinterpret_cast<const int4*>(p)[k];
            hv[k * 4 + 0] += v.x; hv[k * 4 + 1] += v.y;
            hv[k * 4 + 2] += v.z; hv[k * 4 + 3] += v.w;
        }
    }

    int cnt = 0;
    #pragma unroll
    for (int c = 0; c < NC; ++c) cnt += hv[c];

    float ce = 0.0f;
    float w  = 0.0f;
    if (f != 0 && cnt > 0) {
        int ma = 0;
        #pragma unroll
        for (int c = 1; c < NC; ++c) if (hv[c] > hv[ma]) ma = c;
        int mv = 1;
        #pragma unroll
        for (int c = 2; c < NC; ++c) if (hv[c] > hv[mv]) mv = c;
        int vcnt = 0;
        #pragma unroll
        for (int c = 1; c < NC; ++c) vcnt += hv[c];
        const int label = (vcnt > 0) ? mv : ma;

        const float inv = FSCALE_INV / (float)cnt;
        float mean[NC];
        float m = -1e30f;
        #pragma unroll
        for (int c = 0; c < NC; ++c) {
            mean[c] = (float)si[c] * inv;
            m = fmaxf(m, mean[c]);
        }
        float se = 0.0f;
        #pragma unroll
        for (int c = 0; c < NC; ++c) se += expf(mean[c] - m);
        const float logz = m + logf(se);

        float picked = 0.0f;
        #pragma unroll
        for (int c = 0; c < NC; ++c) picked = (c == label) ? mean[c] : picked;

        ce = logz - picked;
        w  = 1.0f;
    }

    #pragma unroll
    for (int off = 32; off > 0; off >>= 1) {
        ce += __shfl_down(ce, off, 64);
        w  += __shfl_down(w,  off, 64);
    }
    __shared__ float rce[4], rw[4];
    const int wid  = threadIdx.x >> 6;
    const int lane = threadIdx.x & 63;
    if (lane == 0) { rce[wid] = ce; rw[wid] = w; }
    __syncthreads();
    if (threadIdx.x == 0) {
        atomicAdd(&tot_n[0], rce[0] + rce[1] + rce[2] + rce[3]);
        atomicAdd(&tot_n[1], rw[0] + rw[1] + rw[2] + rw[3]);
    }
}

// ---------------------------------------------------------------------------
// Kernel 4: final scalar
// ---------------------------------------------------------------------------
__global__ void out_kernel(const float* __restrict__ tot_n, float* __restrict__ out)
{
    const float n = tot_n[1];
    out[0] = (n > 0.0f) ? (tot_n[0] / n) : 0.0f;
}

// ---------------------------------------------------------------------------
extern "C" void kernel_launch(void* const* d_in, const int* in_sizes, int n_in,
                              void* d_out, int out_size, void* d_ws, size_t ws_size,
                              hipStream_t stream)
{
    const float* logits = (const float*)d_in[0];
    const int*   masks  = (const int*)d_in[1];
    const int*   fids   = (const int*)d_in[2];

    const size_t psums_bytes = (size_t)NB * CHS * 2 * FMAX * CGRP * sizeof(int); // 32 MiB
    const size_t phist_bytes = (size_t)NB * CHH * FMAX * NC * sizeof(int);       // 16 MiB
    int*   psums = (int*)d_ws;
    int*   phist = (int*)((char*)d_ws + psums_bytes);
    float* tot_n = (float*)((char*)d_ws + psums_bytes + phist_bytes);

    hipMemsetAsync(tot_n, 0, 2 * sizeof(float), stream);

    sums_kernel<<<NB * CHS * 2, T, 0, stream>>>(logits, fids, psums);
    hist_kernel<<<NB * CHH, T, 0, stream>>>(masks, fids, phist);
    finalize_kernel<<<NB * FMAX / 256, 256, 0, stream>>>(psums, phist, tot_n);
    out_kernel<<<1, 1, 0, stream>>>(tot_n, (float*)d_out);
}

// Round 13
// 425.631 us; speedup vs baseline: 1.5823x; 1.0289x over previous
//
#include <hip/hip_runtime.h>

#define FMAX 1024
#define NC 16       // channels
#define NB 16       // batch
#define HW (512 * 512)

constexpr int CHS = 32;              // pixel chunks per image, sums kernel
constexpr int CHH = 16;              // pixel chunks per image, hist kernel
constexpr int T   = 512;             // threads per block (accum kernels)

// u64-packed fixed-point accumulation: two channels per LDS atomic
// (native ds_add_u64). Each 32-bit half holds sum of (round(v*2^12) + 2^21);
// bias 2^21 keeps every addend positive (no borrow across halves), removed
// in finalize as cnt*2^21. Max biased cell sum ~7e7/chunk, ~7e8/image: safe.
constexpr float FSCALE     = 4096.0f;            // 2^12
constexpr float FSCALE_INV = 1.0f / FSCALE;
constexpr int   QBIAS      = 1 << 21;

// workspace layout:
//   psums : (NB*CHS*2) slabs of [FMAX][4] u64 = 32 MiB   (row f = 4 u64 = 8 ch)
//   phist : (NB*CHH) slabs of [FMAX][16] int32 = 16 MiB
//   tot_n : 2 floats

__device__ __forceinline__ unsigned long long pack2(float a, float b) {
    const unsigned lo = (unsigned)(__float2int_rn(a * FSCALE) + QBIAS);
    const unsigned hi = (unsigned)(__float2int_rn(b * FSCALE) + QBIAS);
    return (unsigned long long)lo | ((unsigned long long)hi << 32);
}

// ---------------------------------------------------------------------------
// Kernel 1: per-(image,chunk,chalf) field sums of 8 channels, LDS-staged,
// u64-packed channel-pair atomics (4 per pixel), 32 KB LDS -> 4 blocks/CU.
// ---------------------------------------------------------------------------
__global__ __launch_bounds__(T, 8) void sums_kernel(
    const float* __restrict__ logits,           // (B, C, HW)
    const int* __restrict__ fids,               // (B, HW)
    unsigned long long* __restrict__ psums)     // (B*CHS*2) x [FMAX][4] u64
{
    __shared__ unsigned long long lsum[4][FMAX];   // 32 KB, [pair][f]

    const int cs = blockIdx.x & 1;              // channel half (8 ch)
    const int bc = blockIdx.x >> 1;             // b*CHS + ch
    const int b  = bc / CHS;
    const int ch = bc % CHS;
    constexpr int PPB = HW / CHS;               // 8192 pixels per block
    const int p0 = ch * PPB;

    for (int i = threadIdx.x; i < 4 * FMAX; i += T)
        lsum[i >> 10][i & (FMAX - 1)] = 0ull;
    __syncthreads();

    const float* lg = logits + (size_t)b * NC * HW + (size_t)(cs * 8) * HW + p0;
    const int*   fb = fids   + (size_t)b * HW + p0;

    constexpr int PASSES = PPB / (T * 4);       // 4
    #pragma unroll
    for (int pass = 0; pass < PASSES; ++pass) {
        const int i4 = (pass * T + threadIdx.x) * 4;
        const int4 f4 = *reinterpret_cast<const int4*>(fb + i4);
        #pragma unroll
        for (int p = 0; p < 4; ++p) {           // channel pair within half
            const float4 ve = *reinterpret_cast<const float4*>(lg + (size_t)(2 * p) * HW + i4);
            const float4 vo = *reinterpret_cast<const float4*>(lg + (size_t)(2 * p + 1) * HW + i4);
            atomicAdd(&lsum[p][f4.x], pack2(ve.x, vo.x));
            atomicAdd(&lsum[p][f4.y], pack2(ve.y, vo.y));
            atomicAdd(&lsum[p][f4.z], pack2(ve.z, vo.z));
            atomicAdd(&lsum[p][f4.w], pack2(ve.w, vo.w));
        }
    }
    __syncthreads();

    // dump transposed: global row f = [p0.lo,p0.hi,p1.lo,p1.hi,...] (32B)
    int4* out = reinterpret_cast<int4*>(psums + (size_t)blockIdx.x * (4 * FMAX));
    for (int j = threadIdx.x; j < 2048; j += T) {
        const int f = j >> 1;
        const int p = (j & 1) * 2;
        const unsigned long long a = lsum[p][f];
        const unsigned long long c = lsum[p + 1][f];
        out[j] = make_int4((int)(unsigned)a, (int)(a >> 32),
                           (int)(unsigned)c, (int)(c >> 32));
    }
}

// ---------------------------------------------------------------------------
// Kernel 2: per-(image,chunk) (field,label) histogram, LDS-staged
// ---------------------------------------------------------------------------
__global__ __launch_bounds__(T) void hist_kernel(
    const int* __restrict__ masks,      // (B, HW)
    const int* __restrict__ fids,       // (B, HW)
    int* __restrict__ phist)            // (B*CHH) x [FMAX][16]
{
    __shared__ int lh[NC * FMAX];       // 64 KB, [lab][f]

    const int b  = blockIdx.x / CHH;
    const int ch = blockIdx.x % CHH;
    constexpr int PPB = HW / CHH;       // 16384
    const int p0 = ch * PPB;

    for (int i = threadIdx.x; i < NC * FMAX; i += T) lh[i] = 0;
    __syncthreads();

    const int* fb = fids  + (size_t)b * HW + p0;
    const int* lb = masks + (size_t)b * HW + p0;

    constexpr int PASSES = PPB / (T * 4);   // 8
    #pragma unroll
    for (int pass = 0; pass < PASSES; ++pass) {
        const int i4 = (pass * T + threadIdx.x) * 4;
        const int4 f4 = *reinterpret_cast<const int4*>(fb + i4);
        const int4 l4 = *reinterpret_cast<const int4*>(lb + i4);
        atomicAdd(&lh[l4.x * FMAX + f4.x], 1);
        atomicAdd(&lh[l4.y * FMAX + f4.y], 1);
        atomicAdd(&lh[l4.z * FMAX + f4.z], 1);
        atomicAdd(&lh[l4.w * FMAX + f4.w], 1);
    }
    __syncthreads();

    // dump transposed: slab row f holds 16 consecutive label counts (64B)
    int* out = phist + (size_t)blockIdx.x * (FMAX * NC);
    for (int j = threadIdx.x; j < FMAX * NC / 4; j += T) {
        const int f  = j >> 2;
        const int c0 = (j & 3) * 4;
        int4 v;
        v.x = lh[(c0 + 0) * FMAX + f];
        v.y = lh[(c0 + 1) * FMAX + f];
        v.z = lh[(c0 + 2) * FMAX + f];
        v.w = lh[(c0 + 3) * FMAX + f];
        reinterpret_cast<int4*>(out)[j] = v;
    }
}

// ---------------------------------------------------------------------------
// Kernel 3: reduce partials (coalesced), per-(b,field) CE vs mode label
// ---------------------------------------------------------------------------
__global__ __launch_bounds__(256) void finalize_kernel(
    const int* __restrict__ psums,      // u64 slabs viewed as int pairs
    const int* __restrict__ phist,
    float* __restrict__ tot_n)          // [0]=total ce, [1]=count
{
    const int idx = blockIdx.x * 256 + threadIdx.x;   // b*FMAX + f
    const int b = idx >> 10;
    const int f = idx & (FMAX - 1);

    int si[NC];
    int hv[NC];
    #pragma unroll
    for (int c = 0; c < NC; ++c) { si[c] = 0; hv[c] = 0; }

    // psums: slab (b*CHS+ch)*2+cs, row f = 8 contiguous ints (2 x int4)
    // int order = ch base+0, +1, ..., +7 (lo/hi interleave == channel order)
    for (int ch = 0; ch < CHS; ++ch) {
        #pragma unroll
        for (int cs = 0; cs < 2; ++cs) {
            const int* p = psums + ((size_t)((b * CHS + ch) * 2 + cs)) * (FMAX * 8)
                         + (size_t)f * 8;
            const int4 a = reinterpret_cast<const int4*>(p)[0];
            const int4 d = reinterpret_cast<const int4*>(p)[1];
            si[cs * 8 + 0] += a.x; si[cs * 8 + 1] += a.y;
            si[cs * 8 + 2] += a.z; si[cs * 8 + 3] += a.w;
            si[cs * 8 + 4] += d.x; si[cs * 8 + 5] += d.y;
            si[cs * 8 + 6] += d.z; si[cs * 8 + 7] += d.w;
        }
    }
    // phist: slab (b*CHH+ch), row f = 16 contiguous ints (4 x int4)
    for (int ch = 0; ch < CHH; ++ch) {
        const int* p = phist + ((size_t)(b * CHH + ch)) * (FMAX * NC) + (size_t)f * NC;
        #pragma unroll
        for (int k = 0; k < 4; ++k) {
            const int4 v = reinterpret_cast<const int4*>(p)[k];
            hv[k * 4 + 0] += v.x; hv[k * 4 + 1] += v.y;
            hv[k * 4 + 2] += v.z; hv[k * 4 + 3] += v.w;
        }
    }

    int cnt = 0;
    #pragma unroll
    for (int c = 0; c < NC; ++c) cnt += hv[c];

    float ce = 0.0f;
    float w  = 0.0f;
    if (f != 0 && cnt > 0) {
        int ma = 0;
        #pragma unroll
        for (int c = 1; c < NC; ++c) if (hv[c] > hv[ma]) ma = c;
        int mv = 1;
        #pragma unroll
        for (int c = 2; c < NC; ++c) if (hv[c] > hv[mv]) mv = c;
        int vcnt = 0;
        #pragma unroll
        for (int c = 1; c < NC; ++c) vcnt += hv[c];
        const int label = (vcnt > 0) ? mv : ma;

        const long long bias = (long long)cnt * (long long)QBIAS;
        const float inv = FSCALE_INV / (float)cnt;
        float mean[NC];
        float m = -1e30f;
        #pragma unroll
        for (int c = 0; c < NC; ++c) {
            mean[c] = (float)((long long)si[c] - bias) * inv;
            m = fmaxf(m, mean[c]);
        }
        float se = 0.0f;
        #pragma unroll
        for (int c = 0; c < NC; ++c) se += expf(mean[c] - m);
        const float logz = m + logf(se);

        float picked = 0.0f;
        #pragma unroll
        for (int c = 0; c < NC; ++c) picked = (c == label) ? mean[c] : picked;

        ce = logz - picked;
        w  = 1.0f;
    }

    #pragma unroll
    for (int off = 32; off > 0; off >>= 1) {
        ce += __shfl_down(ce, off, 64);
        w  += __shfl_down(w,  off, 64);
    }
    __shared__ float rce[4], rw[4];
    const int wid  = threadIdx.x >> 6;
    const int lane = threadIdx.x & 63;
    if (lane == 0) { rce[wid] = ce; rw[wid] = w; }
    __syncthreads();
    if (threadIdx.x == 0) {
        atomicAdd(&tot_n[0], rce[0] + rce[1] + rce[2] + rce[3]);
        atomicAdd(&tot_n[1], rw[0] + rw[1] + rw[2] + rw[3]);
    }
}

// ---------------------------------------------------------------------------
// Kernel 4: final scalar
// ---------------------------------------------------------------------------
__global__ void out_kernel(const float* __restrict__ tot_n, float* __restrict__ out)
{
    const float n = tot_n[1];
    out[0] = (n > 0.0f) ? (tot_n[0] / n) : 0.0f;
}

// ---------------------------------------------------------------------------
extern "C" void kernel_launch(void* const* d_in, const int* in_sizes, int n_in,
                              void* d_out, int out_size, void* d_ws, size_t ws_size,
                              hipStream_t stream)
{
    const float* logits = (const float*)d_in[0];
    const int*   masks  = (const int*)d_in[1];
    const int*   fids   = (const int*)d_in[2];

    const size_t psums_bytes = (size_t)NB * CHS * 2 * FMAX * 4 * sizeof(unsigned long long); // 32 MiB
    const size_t phist_bytes = (size_t)NB * CHH * FMAX * NC * sizeof(int);                   // 16 MiB
    unsigned long long* psums = (unsigned long long*)d_ws;
    int*   phist = (int*)((char*)d_ws + psums_bytes);
    float* tot_n = (float*)((char*)d_ws + psums_bytes + phist_bytes);

    hipMemsetAsync(tot_n, 0, 2 * sizeof(float), stream);

    sums_kernel<<<NB * CHS * 2, T, 0, stream>>>(logits, fids, psums);
    hist_kernel<<<NB * CHH, T, 0, stream>>>(masks, fids, phist);
    finalize_kernel<<<NB * FMAX / 256, 256, 0, stream>>>((const int*)psums, phist, tot_n);
    out_kernel<<<1, 1, 0, stream>>>(tot_n, (float*)d_out);
}